// Round 1
// baseline (1567.502 us; speedup 1.0000x reference)
//
#include <hip/hip_runtime.h>
#include <math.h>

#define B_N 1024
#define D_K 512
#define C_N 100000
#define SCALE 30.0f
#define COS_M 0.9553364891256061f
#define SIN_M 0.29552020666133955f
#define TH_C (-0.9553364891256061f)
#define MM_C 0.08865606199840186f

#define BM 128
#define BN 128
#define BK 16
#define NCT ((C_N + BN - 1) / BN)   // 782

// ---------------- kernel A: reciprocal row norms of weight ----------------
__global__ __launch_bounds__(256) void rnorm_kernel(const float* __restrict__ w,
                                                    float* __restrict__ rnorm) {
    int wave = threadIdx.x >> 6;
    int lane = threadIdx.x & 63;
    int c = blockIdx.x * 4 + wave;
    if (c >= C_N) return;
    const float4* p = (const float4*)(w + (size_t)c * D_K);
    float4 a = p[lane];
    float4 b = p[lane + 64];
    float s = a.x*a.x + a.y*a.y + a.z*a.z + a.w*a.w
            + b.x*b.x + b.y*b.y + b.z*b.z + b.w*b.w;
    #pragma unroll
    for (int off = 32; off; off >>= 1) s += __shfl_xor(s, off, 64);
    if (lane == 0) rnorm[c] = 1.0f / sqrtf(s);
}

__device__ inline void merge_ms(float& m, float& s, float m2, float s2) {
    float M = fmaxf(m, m2);
    if (M != -INFINITY) {
        s = s * __expf(m - M) + s2 * __expf(m2 - M);
        m = M;
    }
}

// ------------- kernel B: tiled GEMM + per-tile online softmax -------------
__global__ __launch_bounds__(256) void gemm_lse_kernel(
    const float* __restrict__ emb, const float* __restrict__ wgt,
    const int* __restrict__ labels, const float* __restrict__ rnorm,
    float2* __restrict__ partial, float* __restrict__ target)
{
    __shared__ float As[BK][BM + 4];
    __shared__ float Bs[BK][BN + 4];
    __shared__ float rnormS[BN];
    __shared__ int   labS[BM];

    const int rt = blockIdx.x;       // 0..7   (row tiles, fast dim for L2 reuse of W)
    const int ct = blockIdx.y;       // 0..781 (class tiles)
    const int row0 = rt * BM;
    const int col0 = ct * BN;
    const int t = threadIdx.x;

    if (t < BN) {
        int c = col0 + t;
        rnormS[t] = (c < C_N) ? rnorm[c] : 0.0f;
    } else {
        labS[t - BN] = labels[row0 + (t - BN)];
    }
    __syncthreads();

    float acc[8][8] = {};
    const int tx = t & 15;           // class dir
    const int ty = t >> 4;           // row dir
    const int lr = t >> 2;           // staging row 0..63
    const int lc = (t & 3) * 4;      // staging k-offset 0/4/8/12

    for (int k0 = 0; k0 < D_K; k0 += BK) {
        #pragma unroll
        for (int p = 0; p < 2; ++p) {
            int r = lr + p * 64;
            float4 v = *(const float4*)(emb + (size_t)(row0 + r) * D_K + k0 + lc);
            As[lc + 0][r] = v.x; As[lc + 1][r] = v.y;
            As[lc + 2][r] = v.z; As[lc + 3][r] = v.w;
        }
        #pragma unroll
        for (int p = 0; p < 2; ++p) {
            int r = lr + p * 64;
            int c = col0 + r;
            float4 v = make_float4(0.f, 0.f, 0.f, 0.f);
            if (c < C_N) v = *(const float4*)(wgt + (size_t)c * D_K + k0 + lc);
            float rn = rnormS[r];
            Bs[lc + 0][r] = v.x * rn; Bs[lc + 1][r] = v.y * rn;
            Bs[lc + 2][r] = v.z * rn; Bs[lc + 3][r] = v.w * rn;
        }
        __syncthreads();
        #pragma unroll
        for (int k = 0; k < BK; ++k) {
            float a[8], b[8];
            #pragma unroll
            for (int i = 0; i < 8; ++i) a[i] = As[k][ty * 8 + i];
            #pragma unroll
            for (int j = 0; j < 8; ++j) b[j] = Bs[k][tx * 8 + j];
            #pragma unroll
            for (int i = 0; i < 8; ++i)
                #pragma unroll
                for (int j = 0; j < 8; ++j)
                    acc[i][j] = fmaf(a[i], b[j], acc[i][j]);
        }
        __syncthreads();
    }

    // epilogue: per-row online softmax partial over this class tile
    #pragma unroll
    for (int i = 0; i < 8; ++i) {
        int b = row0 + ty * 8 + i;
        int lab = labS[ty * 8 + i];
        float m = -INFINITY, s = 0.0f;
        #pragma unroll
        for (int j = 0; j < 8; ++j) {
            int c = col0 + tx * 8 + j;
            if (c >= C_N) continue;
            float cosv = acc[i][j];
            float logit;
            if (c == lab) {
                float sine = sqrtf(fminf(fmaxf(1.0f - cosv * cosv, 0.0f), 1.0f));
                float phi = cosv * COS_M - sine * SIN_M;
                phi = (cosv > TH_C) ? phi : (cosv - MM_C);
                logit = SCALE * phi;
                target[b] = logit;
            } else {
                logit = SCALE * cosv;
            }
            merge_ms(m, s, logit, 1.0f);
        }
        #pragma unroll
        for (int off = 1; off < 16; off <<= 1) {
            float m2 = __shfl_xor(m, off, 16);
            float s2 = __shfl_xor(s, off, 16);
            merge_ms(m, s, m2, s2);
        }
        if (tx == 0) partial[(size_t)b * NCT + ct] = make_float2(m, s);
    }
}

// ------------- kernel C1: combine partials per row → nll[b] -------------
__global__ __launch_bounds__(256) void lse_reduce_kernel(
    const float2* __restrict__ partial, const float* __restrict__ target,
    float* __restrict__ nll)
{
    int b = blockIdx.x;
    int t = threadIdx.x;
    float m = -INFINITY, s = 0.0f;
    for (int ct = t; ct < NCT; ct += 256) {
        float2 p = partial[(size_t)b * NCT + ct];
        merge_ms(m, s, p.x, p.y);
    }
    #pragma unroll
    for (int off = 1; off < 64; off <<= 1) {
        float m2 = __shfl_xor(m, off, 64);
        float s2 = __shfl_xor(s, off, 64);
        merge_ms(m, s, m2, s2);
    }
    __shared__ float ms[4], ss[4];
    int wave = t >> 6, lane = t & 63;
    if (lane == 0) { ms[wave] = m; ss[wave] = s; }
    __syncthreads();
    if (t == 0) {
        m = ms[0]; s = ss[0];
        for (int w = 1; w < 4; ++w) merge_ms(m, s, ms[w], ss[w]);
        nll[b] = (m + logf(s)) - target[b];
    }
}

// ------------- kernel C2: mean over batch -------------
__global__ __launch_bounds__(1024) void mean_kernel(const float* __restrict__ nll,
                                                    float* __restrict__ out) {
    int t = threadIdx.x;
    float v = nll[t];
    #pragma unroll
    for (int off = 1; off < 64; off <<= 1) v += __shfl_xor(v, off, 64);
    __shared__ float ws[16];
    int wave = t >> 6, lane = t & 63;
    if (lane == 0) ws[wave] = v;
    __syncthreads();
    if (t == 0) {
        float sum = 0.f;
        for (int w = 0; w < 16; ++w) sum += ws[w];
        out[0] = sum / (float)B_N;
    }
}

extern "C" void kernel_launch(void* const* d_in, const int* in_sizes, int n_in,
                              void* d_out, int out_size, void* d_ws, size_t ws_size,
                              hipStream_t stream) {
    const float* emb    = (const float*)d_in[0];
    const int*   labels = (const int*)d_in[1];
    const float* wgt    = (const float*)d_in[2];
    float* out = (float*)d_out;

    char* ws = (char*)d_ws;
    float*  rnorm   = (float*)(ws);                       // 400000 B
    float*  target  = (float*)(ws + 400000);              // 4096 B
    float*  nll     = (float*)(ws + 404096);              // 4096 B
    float2* partial = (float2*)(ws + 408192);             // 1024*782*8 = 6406144 B

    rnorm_kernel<<<C_N / 4, 256, 0, stream>>>(wgt, rnorm);
    dim3 gridB(B_N / BM, NCT);
    gemm_lse_kernel<<<gridB, 256, 0, stream>>>(emb, wgt, labels, rnorm, partial, target);
    lse_reduce_kernel<<<B_N, 256, 0, stream>>>(partial, target, nll);
    mean_kernel<<<1, 1024, 0, stream>>>(nll, out);
}

// Round 2
// 572.517 us; speedup vs baseline: 2.7379x; 2.7379x over previous
//
#include <hip/hip_runtime.h>
#include <math.h>

#define B_N 1024
#define D_K 512
#define C_N 100000
#define SCALEF 30.0f
#define COS_M 0.9553364891256061f
#define SIN_M 0.29552020666133955f
#define TH_C (-0.9553364891256061f)
#define MM_C 0.08865606199840186f

#define BM 128
#define BN 128
#define NCT ((C_N + BN - 1) / BN)   // 782
#define ROWS 40                     // shorts per LDS tile row (80 B = 64 B data + 16 B pad)

typedef short bf16x8 __attribute__((ext_vector_type(8)));
typedef float f32x4  __attribute__((ext_vector_type(4)));

__device__ inline unsigned bf16rne(float f) {
    unsigned u = __float_as_uint(f);
    u += 0x7fffu + ((u >> 16) & 1u);
    return u >> 16;
}
__device__ inline unsigned pk2(float lo, float hi) {
    return bf16rne(lo) | (bf16rne(hi) << 16);
}

// ---------------- kernel A: reciprocal row norms of weight ----------------
__global__ __launch_bounds__(256) void rnorm_kernel(const float* __restrict__ w,
                                                    float* __restrict__ rnorm) {
    int wave = threadIdx.x >> 6;
    int lane = threadIdx.x & 63;
    int c = blockIdx.x * 4 + wave;
    if (c >= C_N) return;
    const float4* p = (const float4*)(w + (size_t)c * D_K);
    float4 a = p[lane];
    float4 b = p[lane + 64];
    float s = a.x*a.x + a.y*a.y + a.z*a.z + a.w*a.w
            + b.x*b.x + b.y*b.y + b.z*b.z + b.w*b.w;
    #pragma unroll
    for (int off = 32; off; off >>= 1) s += __shfl_xor(s, off, 64);
    if (lane == 0) rnorm[c] = 1.0f / sqrtf(s);
}

// ---------------- kernel A2: embeddings f32 -> bf16 ----------------
__global__ __launch_bounds__(256) void embcvt_kernel(const float* __restrict__ e,
                                                     unsigned short* __restrict__ ebf) {
    int i = blockIdx.x * 256 + threadIdx.x;   // 131072 threads, 4 floats each
    float4 v = ((const float4*)e)[i];
    uint2 o;
    o.x = pk2(v.x, v.y);
    o.y = pk2(v.z, v.w);
    ((uint2*)ebf)[i] = o;
}

__device__ inline void merge_ms(float& m, float& s, float m2, float s2) {
    float M = fmaxf(m, m2);
    if (M != -INFINITY) {
        s = s * __expf(m - M) + s2 * __expf(m2 - M);
        m = M;
    }
}

// ------------- kernel B: MFMA GEMM + per-tile online softmax -------------
__global__ __launch_bounds__(256) void gemm_lse_kernel(
    const unsigned short* __restrict__ ebf, const float* __restrict__ wgt,
    const int* __restrict__ labels, const float* __restrict__ rnorm,
    float2* __restrict__ partial, float* __restrict__ target)
{
    __shared__ short As[BM * ROWS];
    __shared__ short Bs[BN * ROWS];
    __shared__ float rnS[BN];
    __shared__ int   labS[BM];
    __shared__ float2 msS[BM][2];

    const int rt = blockIdx.x;      // 0..7  row tiles (fast dim: 8 blocks share W tile)
    const int ct = blockIdx.y;      // 0..781 class tiles
    const int row0 = rt * BM;
    const int col0 = ct * BN;
    const int t = threadIdx.x;
    const int lane = t & 63, wave = t >> 6;
    const int wx = wave & 1, wy = wave >> 1;   // wave covers rows wy*64.., cols wx*64..
    const int lc = lane & 15, q = lane >> 4;

    if (t < BN) {
        int c = col0 + t;
        rnS[t] = (c < C_N) ? rnorm[c] : 0.0f;
    } else {
        labS[t - BN] = labels[row0 + (t - BN)];
    }
    __syncthreads();

    // staging mapping: thread t -> tile row sr = t>>1, half sh = t&1 (16 elements)
    const int sr = t >> 1;
    const int sh = t & 1;
    const int cB = col0 + sr;
    const bool bval = cB < C_N;
    const float rn = rnS[sr];
    const unsigned short* aptr = ebf + (size_t)(row0 + sr) * D_K + sh * 16;
    const float* bptr0 = wgt + (size_t)cB * D_K + sh * 16;

    f32x4 acc[4][4] = {};

    for (int it = 0; it < D_K / 32; ++it) {
        const int k0 = it * 32;
        // global loads (before barrier, hide latency)
        uint4 a0 = ((const uint4*)(aptr + k0))[0];
        uint4 a1 = ((const uint4*)(aptr + k0))[1];
        float4 b0 = make_float4(0.f,0.f,0.f,0.f), b1 = b0, b2 = b0, b3 = b0;
        if (bval) {
            const float4* bp = (const float4*)(bptr0 + k0);
            b0 = bp[0]; b1 = bp[1]; b2 = bp[2]; b3 = bp[3];
        }
        uint4 w0, w1;
        w0.x = pk2(b0.x * rn, b0.y * rn); w0.y = pk2(b0.z * rn, b0.w * rn);
        w0.z = pk2(b1.x * rn, b1.y * rn); w0.w = pk2(b1.z * rn, b1.w * rn);
        w1.x = pk2(b2.x * rn, b2.y * rn); w1.y = pk2(b2.z * rn, b2.w * rn);
        w1.z = pk2(b3.x * rn, b3.y * rn); w1.w = pk2(b3.z * rn, b3.w * rn);

        __syncthreads();   // previous iter's fragment reads complete
        *(uint4*)(As + sr * ROWS + sh * 16)     = a0;
        *(uint4*)(As + sr * ROWS + sh * 16 + 8) = a1;
        *(uint4*)(Bs + sr * ROWS + sh * 16)     = w0;
        *(uint4*)(Bs + sr * ROWS + sh * 16 + 8) = w1;
        __syncthreads();   // tiles ready

        bf16x8 aF[4], bF[4];
        #pragma unroll
        for (int si = 0; si < 4; ++si)
            aF[si] = *(const bf16x8*)(As + (wy * 64 + si * 16 + lc) * ROWS + q * 8);
        #pragma unroll
        for (int sj = 0; sj < 4; ++sj)
            bF[sj] = *(const bf16x8*)(Bs + (wx * 64 + sj * 16 + lc) * ROWS + q * 8);
        #pragma unroll
        for (int si = 0; si < 4; ++si)
            #pragma unroll
            for (int sj = 0; sj < 4; ++sj)
                acc[si][sj] = __builtin_amdgcn_mfma_f32_16x16x32_bf16(
                    aF[si], bF[sj], acc[si][sj], 0, 0, 0);
    }

    // ---- epilogue: per-row online softmax over this wave's 64 cols ----
    // C/D layout: col = lane&15, row = quad*4 + reg
    #pragma unroll
    for (int si = 0; si < 4; ++si) {
        #pragma unroll
        for (int reg = 0; reg < 4; ++reg) {
            int rl = wy * 64 + si * 16 + q * 4 + reg;
            int lab = labS[rl];
            float lg[4];
            float mx = -INFINITY;
            #pragma unroll
            for (int sj = 0; sj < 4; ++sj) {
                int cg = col0 + wx * 64 + sj * 16 + lc;
                float cosv = acc[si][sj][reg];
                float v;
                if (cg == lab) {
                    float sine = sqrtf(fminf(fmaxf(1.0f - cosv * cosv, 0.0f), 1.0f));
                    float phi = cosv * COS_M - sine * SIN_M;
                    phi = (cosv > TH_C) ? phi : (cosv - MM_C);
                    v = SCALEF * phi;
                    target[row0 + rl] = v;
                } else {
                    v = SCALEF * cosv;
                }
                if (cg >= C_N) v = -INFINITY;
                lg[sj] = v;
                mx = fmaxf(mx, v);
            }
            #pragma unroll
            for (int off = 1; off < 16; off <<= 1)
                mx = fmaxf(mx, __shfl_xor(mx, off, 64));
            float s = 0.0f;
            #pragma unroll
            for (int sj = 0; sj < 4; ++sj)
                if (lg[sj] != -INFINITY) s += __expf(lg[sj] - mx);
            #pragma unroll
            for (int off = 1; off < 16; off <<= 1)
                s += __shfl_xor(s, off, 64);
            if (lc == 0) msS[rl][wx] = make_float2(mx, s);
        }
    }
    __syncthreads();
    if (t < BM) {
        float2 p0 = msS[t][0], p1 = msS[t][1];
        float m = p0.x, s = p0.y;
        float M = fmaxf(m, p1.x);
        if (M != -INFINITY) {
            s = s * __expf(m - M) + p1.y * __expf(p1.x - M);
            m = M;
        }
        partial[(size_t)(row0 + t) * NCT + ct] = make_float2(m, s);
    }
}

// ------------- kernel C1: combine partials per row -> nll[b] -------------
__global__ __launch_bounds__(256) void lse_reduce_kernel(
    const float2* __restrict__ partial, const float* __restrict__ target,
    float* __restrict__ nll)
{
    int b = blockIdx.x;
    int t = threadIdx.x;
    float m = -INFINITY, s = 0.0f;
    for (int ct = t; ct < NCT; ct += 256) {
        float2 p = partial[(size_t)b * NCT + ct];
        merge_ms(m, s, p.x, p.y);
    }
    #pragma unroll
    for (int off = 1; off < 64; off <<= 1) {
        float m2 = __shfl_xor(m, off, 64);
        float s2 = __shfl_xor(s, off, 64);
        merge_ms(m, s, m2, s2);
    }
    __shared__ float ms[4], ss[4];
    int wave = t >> 6, lane = t & 63;
    if (lane == 0) { ms[wave] = m; ss[wave] = s; }
    __syncthreads();
    if (t == 0) {
        m = ms[0]; s = ss[0];
        for (int w = 1; w < 4; ++w) merge_ms(m, s, ms[w], ss[w]);
        nll[b] = (m + logf(s)) - target[b];
    }
}

// ------------- kernel C2: mean over batch -------------
__global__ __launch_bounds__(1024) void mean_kernel(const float* __restrict__ nll,
                                                    float* __restrict__ out) {
    int t = threadIdx.x;
    float v = nll[t];
    #pragma unroll
    for (int off = 1; off < 64; off <<= 1) v += __shfl_xor(v, off, 64);
    __shared__ float ws[16];
    int wave = t >> 6, lane = t & 63;
    if (lane == 0) ws[wave] = v;
    __syncthreads();
    if (t == 0) {
        float sum = 0.f;
        for (int w = 0; w < 16; ++w) sum += ws[w];
        out[0] = sum / (float)B_N;
    }
}

extern "C" void kernel_launch(void* const* d_in, const int* in_sizes, int n_in,
                              void* d_out, int out_size, void* d_ws, size_t ws_size,
                              hipStream_t stream) {
    const float* emb    = (const float*)d_in[0];
    const int*   labels = (const int*)d_in[1];
    const float* wgt    = (const float*)d_in[2];
    float* out = (float*)d_out;

    char* ws = (char*)d_ws;
    float*  rnorm   = (float*)(ws);                       // 400000 B
    float*  target  = (float*)(ws + 400000);              // 4096 B
    float*  nll     = (float*)(ws + 404096);              // 4096 B
    float2* partial = (float2*)(ws + 408192);             // 1024*782*8 = 6406144 B
    unsigned short* ebf = (unsigned short*)(ws + 6814336);// 1024*512*2 = 1048576 B

    rnorm_kernel<<<C_N / 4, 256, 0, stream>>>(wgt, rnorm);
    embcvt_kernel<<<(B_N * D_K / 4) / 256, 256, 0, stream>>>(emb, ebf);
    dim3 gridB(B_N / BM, NCT);
    gemm_lse_kernel<<<gridB, 256, 0, stream>>>(ebf, wgt, labels, rnorm, partial, target);
    lse_reduce_kernel<<<B_N, 256, 0, stream>>>(partial, target, nll);
    mean_kernel<<<1, 1024, 0, stream>>>(nll, out);
}

// Round 3
// 455.063 us; speedup vs baseline: 3.4446x; 1.2581x over previous
//
#include <hip/hip_runtime.h>
#include <math.h>

#define B_N 1024
#define D_K 512
#define C_N 100000
#define SCALEF 30.0f
#define COS_M 0.9553364891256061f
#define SIN_M 0.29552020666133955f
#define TH_C (-0.9553364891256061f)
#define MM_C 0.08865606199840186f
#define FIXM 160.0f

#define BM 128
#define BN 128
#define NCT ((C_N + BN - 1) / BN)   // 782
#define NCTP 784                    // padded to multiple of 8 for XCD swizzle

typedef short bf16x8 __attribute__((ext_vector_type(8)));
typedef float f32x4  __attribute__((ext_vector_type(4)));

__device__ inline unsigned bf16rne(float f) {
    unsigned u = __float_as_uint(f);
    u += 0x7fffu + ((u >> 16) & 1u);
    return u >> 16;
}
__device__ inline unsigned pk2(float lo, float hi) {
    return bf16rne(lo) | (bf16rne(hi) << 16);
}

__device__ static __forceinline__ void async16(const void* g, void* l) {
    __builtin_amdgcn_global_load_lds(
        (const __attribute__((address_space(1))) unsigned int*)g,
        (__attribute__((address_space(3))) unsigned int*)l, 16, 0, 0);
}

// ---------- kernel W: fused row-norm + f32->bf16 convert of weight ----------
__global__ __launch_bounds__(256) void wcvt_kernel(const float* __restrict__ w,
                                                   unsigned short* __restrict__ wbf) {
    int wave = threadIdx.x >> 6;
    int lane = threadIdx.x & 63;
    int c = blockIdx.x * 4 + wave;
    if (c >= C_N) return;
    const float4* p = (const float4*)(w + (size_t)c * D_K);
    float4 a = p[lane];
    float4 b = p[lane + 64];
    float s = a.x*a.x + a.y*a.y + a.z*a.z + a.w*a.w
            + b.x*b.x + b.y*b.y + b.z*b.z + b.w*b.w;
    #pragma unroll
    for (int off = 32; off; off >>= 1) s += __shfl_xor(s, off, 64);
    float rn = 1.0f / sqrtf(s);
    uint2 o0, o1;
    o0.x = pk2(a.x * rn, a.y * rn); o0.y = pk2(a.z * rn, a.w * rn);
    o1.x = pk2(b.x * rn, b.y * rn); o1.y = pk2(b.z * rn, b.w * rn);
    uint2* q = (uint2*)(wbf + (size_t)c * D_K);
    q[lane] = o0;
    q[lane + 64] = o1;
}

// ---------------- kernel A2: embeddings f32 -> bf16 ----------------
__global__ __launch_bounds__(256) void embcvt_kernel(const float* __restrict__ e,
                                                     unsigned short* __restrict__ ebf) {
    int i = blockIdx.x * 256 + threadIdx.x;
    float4 v = ((const float4*)e)[i];
    uint2 o;
    o.x = pk2(v.x, v.y);
    o.y = pk2(v.z, v.w);
    ((uint2*)ebf)[i] = o;
}

// ------------- kernel B: MFMA GEMM (global_load_lds) + fixed-max partial sums -------------
__global__ __launch_bounds__(256) void gemm_lse_kernel(
    const unsigned short* __restrict__ ebf, const unsigned short* __restrict__ wbf,
    const int* __restrict__ labels,
    float* __restrict__ partial, float* __restrict__ target)
{
    __shared__ short As[BM * 32];
    __shared__ short Bs[BN * 32];
    __shared__ int   labS[BM];
    __shared__ float sS[BM][2];

    // XCD swizzle: bid = 64g + 8r + j -> ct = 8g+j (same XCD processes all 8 r's of a ct)
    const int bid = blockIdx.x;
    const int g = bid >> 6, r = (bid >> 3) & 7, j = bid & 7;
    const int ct = g * 8 + j;        // 0..783 (782,783 are dummy)
    const int rt = r;
    const int row0 = rt * BM;
    const int col0 = ct * BN;
    const int t = threadIdx.x;
    const int lane = t & 63, wave = t >> 6;
    const int wx = wave & 1, wy = wave >> 1;
    const int lc = lane & 15, q = lane >> 4;

    if (t < BM) labS[t] = labels[row0 + t];
    __syncthreads();

    // staging: chunk c in [0,512): row = c>>2, k-chunk = (c&3)*8 elems (16 B)
    const int srow = t >> 2, skc = (t & 3) * 8;
    const unsigned short* aptr = ebf + (size_t)(row0 + srow) * D_K + skc;
    int brow0 = col0 + srow;        if (brow0 >= C_N) brow0 = C_N - 1;
    int brow1 = col0 + 64 + srow;   if (brow1 >= C_N) brow1 = C_N - 1;
    const unsigned short* bptr0 = wbf + (size_t)brow0 * D_K + skc;
    const unsigned short* bptr1 = wbf + (size_t)brow1 * D_K + skc;
    short* ldsA0 = As + t * 8;
    short* ldsA1 = As + t * 8 + 2048;
    short* ldsB0 = Bs + t * 8;
    short* ldsB1 = Bs + t * 8 + 2048;

    f32x4 acc[4][4] = {};

    for (int it = 0; it < D_K / 32; ++it) {
        const int k0 = it * 32;
        __syncthreads();   // previous iter's fragment reads complete
        async16(aptr + k0, ldsA0);
        async16(aptr + 64 * D_K + k0, ldsA1);
        async16(bptr0 + k0, ldsB0);
        async16(bptr1 + k0, ldsB1);
        __syncthreads();   // drains vmcnt -> tiles ready

        bf16x8 aF[4], bF[4];
        #pragma unroll
        for (int si = 0; si < 4; ++si)
            aF[si] = *(const bf16x8*)(As + (wy * 64 + si * 16 + lc) * 32 + q * 8);
        #pragma unroll
        for (int sj = 0; sj < 4; ++sj)
            bF[sj] = *(const bf16x8*)(Bs + (wx * 64 + sj * 16 + lc) * 32 + q * 8);
        #pragma unroll
        for (int si = 0; si < 4; ++si)
            #pragma unroll
            for (int sj = 0; sj < 4; ++sj)
                acc[si][sj] = __builtin_amdgcn_mfma_f32_16x16x32_bf16(
                    aF[si], bF[sj], acc[si][sj], 0, 0, 0);
    }

    // ---- epilogue: fixed-max exp-sum over this wave's 64 cols ----
    // C/D layout: col = lane&15, row = quad*4 + reg
    #pragma unroll
    for (int si = 0; si < 4; ++si) {
        #pragma unroll
        for (int reg = 0; reg < 4; ++reg) {
            int rl = wy * 64 + si * 16 + q * 4 + reg;
            int lab = labS[rl];
            float s = 0.0f;
            #pragma unroll
            for (int sj = 0; sj < 4; ++sj) {
                int cg = col0 + wx * 64 + sj * 16 + lc;
                float cosv = acc[si][sj][reg];
                float v;
                if (cg == lab) {
                    float sine = sqrtf(fminf(fmaxf(1.0f - cosv * cosv, 0.0f), 1.0f));
                    float phi = cosv * COS_M - sine * SIN_M;
                    phi = (cosv > TH_C) ? phi : (cosv - MM_C);
                    v = SCALEF * phi;
                    target[row0 + rl] = v;
                } else {
                    v = SCALEF * cosv;
                }
                if (cg < C_N) s += __expf(v - FIXM);
            }
            #pragma unroll
            for (int off = 1; off < 16; off <<= 1)
                s += __shfl_xor(s, off, 64);
            if (lc == 0) sS[rl][wx] = s;
        }
    }
    __syncthreads();
    if (t < BM && ct < NCT)
        partial[(size_t)(row0 + t) * NCT + ct] = sS[t][0] + sS[t][1];
}

// ------------- kernel C1: sum partials per row -> nll[b] -------------
__global__ __launch_bounds__(256) void lse_reduce_kernel(
    const float* __restrict__ partial, const float* __restrict__ target,
    float* __restrict__ nll)
{
    int b = blockIdx.x;
    int t = threadIdx.x;
    float s = 0.0f;
    for (int ct = t; ct < NCT; ct += 256) s += partial[(size_t)b * NCT + ct];
    #pragma unroll
    for (int off = 1; off < 64; off <<= 1) s += __shfl_xor(s, off, 64);
    __shared__ float ss[4];
    int wave = t >> 6, lane = t & 63;
    if (lane == 0) ss[wave] = s;
    __syncthreads();
    if (t == 0) {
        s = ss[0] + ss[1] + ss[2] + ss[3];
        nll[b] = (FIXM + logf(s)) - target[b];
    }
}

// ------------- kernel C2: mean over batch -------------
__global__ __launch_bounds__(1024) void mean_kernel(const float* __restrict__ nll,
                                                    float* __restrict__ out) {
    int t = threadIdx.x;
    float v = nll[t];
    #pragma unroll
    for (int off = 1; off < 64; off <<= 1) v += __shfl_xor(v, off, 64);
    __shared__ float ws[16];
    int wave = t >> 6, lane = t & 63;
    if (lane == 0) ws[wave] = v;
    __syncthreads();
    if (t == 0) {
        float sum = 0.f;
        for (int w = 0; w < 16; ++w) sum += ws[w];
        out[0] = sum / (float)B_N;
    }
}

// ===================== fallback path (round-2, small ws) =====================
__global__ __launch_bounds__(256) void rnorm_fb_kernel(const float* __restrict__ w,
                                                       float* __restrict__ rnorm) {
    int wave = threadIdx.x >> 6;
    int lane = threadIdx.x & 63;
    int c = blockIdx.x * 4 + wave;
    if (c >= C_N) return;
    const float4* p = (const float4*)(w + (size_t)c * D_K);
    float4 a = p[lane];
    float4 b = p[lane + 64];
    float s = a.x*a.x + a.y*a.y + a.z*a.z + a.w*a.w
            + b.x*b.x + b.y*b.y + b.z*b.z + b.w*b.w;
    #pragma unroll
    for (int off = 32; off; off >>= 1) s += __shfl_xor(s, off, 64);
    if (lane == 0) rnorm[c] = 1.0f / sqrtf(s);
}

__device__ inline void merge_ms(float& m, float& s, float m2, float s2) {
    float M = fmaxf(m, m2);
    if (M != -INFINITY) {
        s = s * __expf(m - M) + s2 * __expf(m2 - M);
        m = M;
    }
}

#define ROWS 40
__global__ __launch_bounds__(256) void gemm_lse_fb_kernel(
    const unsigned short* __restrict__ ebf, const float* __restrict__ wgt,
    const int* __restrict__ labels, const float* __restrict__ rnorm,
    float2* __restrict__ partial, float* __restrict__ target)
{
    __shared__ short As[BM * ROWS];
    __shared__ short Bs[BN * ROWS];
    __shared__ float rnS[BN];
    __shared__ int   labS[BM];
    __shared__ float2 msS[BM][2];

    const int rt = blockIdx.x;
    const int ct = blockIdx.y;
    const int row0 = rt * BM;
    const int col0 = ct * BN;
    const int t = threadIdx.x;
    const int lane = t & 63, wave = t >> 6;
    const int wx = wave & 1, wy = wave >> 1;
    const int lc = lane & 15, q = lane >> 4;

    if (t < BN) {
        int c = col0 + t;
        rnS[t] = (c < C_N) ? rnorm[c] : 0.0f;
    } else {
        labS[t - BN] = labels[row0 + (t - BN)];
    }
    __syncthreads();

    const int sr = t >> 1;
    const int sh = t & 1;
    const int cB = col0 + sr;
    const bool bval = cB < C_N;
    const float rn = rnS[sr];
    const unsigned short* aptr = ebf + (size_t)(row0 + sr) * D_K + sh * 16;
    const float* bptr0 = wgt + (size_t)(bval ? cB : 0) * D_K + sh * 16;

    f32x4 acc[4][4] = {};

    for (int it = 0; it < D_K / 32; ++it) {
        const int k0 = it * 32;
        uint4 a0 = ((const uint4*)(aptr + k0))[0];
        uint4 a1 = ((const uint4*)(aptr + k0))[1];
        float4 b0 = make_float4(0.f,0.f,0.f,0.f), b1 = b0, b2 = b0, b3 = b0;
        if (bval) {
            const float4* bp = (const float4*)(bptr0 + k0);
            b0 = bp[0]; b1 = bp[1]; b2 = bp[2]; b3 = bp[3];
        }
        uint4 w0, w1;
        w0.x = pk2(b0.x * rn, b0.y * rn); w0.y = pk2(b0.z * rn, b0.w * rn);
        w0.z = pk2(b1.x * rn, b1.y * rn); w0.w = pk2(b1.z * rn, b1.w * rn);
        w1.x = pk2(b2.x * rn, b2.y * rn); w1.y = pk2(b2.z * rn, b2.w * rn);
        w1.z = pk2(b3.x * rn, b3.y * rn); w1.w = pk2(b3.z * rn, b3.w * rn);

        __syncthreads();
        *(uint4*)(As + sr * ROWS + sh * 16)     = a0;
        *(uint4*)(As + sr * ROWS + sh * 16 + 8) = a1;
        *(uint4*)(Bs + sr * ROWS + sh * 16)     = w0;
        *(uint4*)(Bs + sr * ROWS + sh * 16 + 8) = w1;
        __syncthreads();

        bf16x8 aF[4], bF[4];
        #pragma unroll
        for (int si = 0; si < 4; ++si)
            aF[si] = *(const bf16x8*)(As + (wy * 64 + si * 16 + lc) * ROWS + q * 8);
        #pragma unroll
        for (int sj = 0; sj < 4; ++sj)
            bF[sj] = *(const bf16x8*)(Bs + (wx * 64 + sj * 16 + lc) * ROWS + q * 8);
        #pragma unroll
        for (int si = 0; si < 4; ++si)
            #pragma unroll
            for (int sj = 0; sj < 4; ++sj)
                acc[si][sj] = __builtin_amdgcn_mfma_f32_16x16x32_bf16(
                    aF[si], bF[sj], acc[si][sj], 0, 0, 0);
    }

    #pragma unroll
    for (int si = 0; si < 4; ++si) {
        #pragma unroll
        for (int reg = 0; reg < 4; ++reg) {
            int rl = wy * 64 + si * 16 + q * 4 + reg;
            int lab = labS[rl];
            float lg[4];
            float mx = -INFINITY;
            #pragma unroll
            for (int sj = 0; sj < 4; ++sj) {
                int cg = col0 + wx * 64 + sj * 16 + lc;
                float cosv = acc[si][sj][reg];
                float v;
                if (cg == lab) {
                    float sine = sqrtf(fminf(fmaxf(1.0f - cosv * cosv, 0.0f), 1.0f));
                    float phi = cosv * COS_M - sine * SIN_M;
                    phi = (cosv > TH_C) ? phi : (cosv - MM_C);
                    v = SCALEF * phi;
                    target[row0 + rl] = v;
                } else {
                    v = SCALEF * cosv;
                }
                if (cg >= C_N) v = -INFINITY;
                lg[sj] = v;
                mx = fmaxf(mx, v);
            }
            #pragma unroll
            for (int off = 1; off < 16; off <<= 1)
                mx = fmaxf(mx, __shfl_xor(mx, off, 64));
            float s = 0.0f;
            #pragma unroll
            for (int sj = 0; sj < 4; ++sj)
                if (lg[sj] != -INFINITY) s += __expf(lg[sj] - mx);
            #pragma unroll
            for (int off = 1; off < 16; off <<= 1)
                s += __shfl_xor(s, off, 64);
            if (lc == 0) msS[rl][wx] = make_float2(mx, s);
        }
    }
    __syncthreads();
    if (t < BM) {
        float2 p0 = msS[t][0], p1 = msS[t][1];
        float m = p0.x, s = p0.y;
        float M = fmaxf(m, p1.x);
        if (M != -INFINITY) {
            s = s * __expf(m - M) + p1.y * __expf(p1.x - M);
            m = M;
        }
        partial[(size_t)(row0 + t) * NCT + ct] = make_float2(m, s);
    }
}

__global__ __launch_bounds__(256) void lse_reduce_fb_kernel(
    const float2* __restrict__ partial, const float* __restrict__ target,
    float* __restrict__ nll)
{
    int b = blockIdx.x;
    int t = threadIdx.x;
    float m = -INFINITY, s = 0.0f;
    for (int ct = t; ct < NCT; ct += 256) {
        float2 p = partial[(size_t)b * NCT + ct];
        merge_ms(m, s, p.x, p.y);
    }
    #pragma unroll
    for (int off = 1; off < 64; off <<= 1) {
        float m2 = __shfl_xor(m, off, 64);
        float s2 = __shfl_xor(s, off, 64);
        merge_ms(m, s, m2, s2);
    }
    __shared__ float ms[4], ss[4];
    int wave = t >> 6, lane = t & 63;
    if (lane == 0) { ms[wave] = m; ss[wave] = s; }
    __syncthreads();
    if (t == 0) {
        m = ms[0]; s = ss[0];
        for (int w = 1; w < 4; ++w) merge_ms(m, s, ms[w], ss[w]);
        nll[b] = (m + logf(s)) - target[b];
    }
}

extern "C" void kernel_launch(void* const* d_in, const int* in_sizes, int n_in,
                              void* d_out, int out_size, void* d_ws, size_t ws_size,
                              hipStream_t stream) {
    const float* emb    = (const float*)d_in[0];
    const int*   labels = (const int*)d_in[1];
    const float* wgt    = (const float*)d_in[2];
    float* out = (float*)d_out;
    char* ws = (char*)d_ws;

    if (ws_size >= 106659840ull) {
        // ---- fast path: bf16 weight copy in workspace ----
        float* target        = (float*)(ws);                    // 4096
        float* nll           = (float*)(ws + 4096);             // 4096
        float* partial       = (float*)(ws + 8192);             // 1024*782*4 = 3203072
        unsigned short* ebf  = (unsigned short*)(ws + 3211264); // 1048576
        unsigned short* wbf  = (unsigned short*)(ws + 4259840); // 102400000

        wcvt_kernel<<<C_N / 4, 256, 0, stream>>>(wgt, wbf);
        embcvt_kernel<<<(B_N * D_K / 4) / 256, 256, 0, stream>>>(emb, ebf);
        gemm_lse_kernel<<<(NCTP / 8) * 64, 256, 0, stream>>>(ebf, wbf, labels, partial, target);
        lse_reduce_kernel<<<B_N, 256, 0, stream>>>(partial, target, nll);
        mean_kernel<<<1, 1024, 0, stream>>>(nll, out);
    } else {
        // ---- fallback: round-2 structure ----
        float*  rnorm   = (float*)(ws);                        // 400000
        float*  target  = (float*)(ws + 400000);               // 4096
        float*  nll     = (float*)(ws + 404096);               // 4096
        float2* partial = (float2*)(ws + 408192);              // 6406144
        unsigned short* ebf = (unsigned short*)(ws + 6814336); // 1048576

        rnorm_fb_kernel<<<C_N / 4, 256, 0, stream>>>(wgt, rnorm);
        embcvt_kernel<<<(B_N * D_K / 4) / 256, 256, 0, stream>>>(emb, ebf);
        dim3 gridB(B_N / BM, NCT);
        gemm_lse_fb_kernel<<<gridB, 256, 0, stream>>>(ebf, wgt, labels, rnorm, partial, target);
        lse_reduce_fb_kernel<<<B_N, 256, 0, stream>>>(partial, target, nll);
        mean_kernel<<<1, 1024, 0, stream>>>(nll, out);
    }
}